// Round 11
// baseline (285.249 us; speedup 1.0000x reference)
//
#include <hip/hip_runtime.h>
#include <stdint.h>

#define NN 4096
#define MM 8192
#define DD 512

typedef __bf16 bf16x8 __attribute__((ext_vector_type(8)));
typedef float f32x4 __attribute__((ext_vector_type(4)));
typedef float f32x16 __attribute__((ext_vector_type(16)));

__device__ __forceinline__ void load_lds16(const void* g, void* l) {
  // async global -> LDS, 16B/lane; LDS dest must be wave-uniform base + lane*16.
  __builtin_amdgcn_global_load_lds(
      (const __attribute__((address_space(1))) unsigned int*)g,
      (__attribute__((address_space(3))) unsigned int*)l, 16, 0, 0);
}

// VALU-pipe partial reduction (R7-verified correct): x += rot16(x, k).
template <int CTRL>
__device__ __forceinline__ float dpp_radd(float x) {
  int xi = __float_as_int(x);
  int mv = __builtin_amdgcn_update_dpp(xi, xi, CTRL, 0xF, 0xF, false);
  return x + __int_as_float(mv);
}
__device__ __forceinline__ float swz_add_xor16(float x) {
  int sv = __builtin_amdgcn_ds_swizzle(__float_as_int(x), 0x401F);
  return x + __int_as_float(sv);
}

// One block per 32-row group. Phase 1: one wave per 8 rows, coalesced f32x4
// reads, fp32 norms, bf16 rows parked in LDS (rotated to kill phase-2 bank
// aliasing). Phase 2: cooperative COALESCED write of the 32 KB frag-order
// region (R10's direct scatter had 512 B lane stride -> 4x write-amp).
// Frag layout (R9/R10-numerically-verified):
//   F[rg*2048 + sg*64 + h*32 + r31] = row (rg*32+r31), elems [(sg*2+h)*8..+8)
__global__ __launch_bounds__(256) void convert_norm_kernel(
    const float* __restrict__ X, const float* __restrict__ SV,
    bf16x8* __restrict__ Xf, bf16x8* __restrict__ SVf,
    float* __restrict__ x2, float* __restrict__ sv2,
    float* __restrict__ out, const float* __restrict__ IC) {
  __shared__ bf16x8 L[2048];  // 32 KB
  const int g = blockIdx.x;   // 0..(128+256-1)
  const bool isX = g < (NN / 32);
  const int rg = isX ? g : g - (NN / 32);
  const float* src = (isX ? X : SV) + (size_t)rg * 32 * DD;
  bf16x8* dstF = (isX ? Xf : SVf) + (size_t)rg * 2048;
  float* nrm = (isX ? x2 : sv2) + rg * 32;
  const int t = threadIdx.x;
  const int lane = t & 63, wv = t >> 6;

  if (isX && t < 32) out[rg * 32 + t] = IC[0];

#pragma unroll
  for (int i = 0; i < 8; ++i) {
    const int r = wv * 8 + i;
    const f32x4* s = (const f32x4*)(src + (size_t)r * DD);
    f32x4 a = s[2 * lane];      // elems 8l..8l+3
    f32x4 b = s[2 * lane + 1];  // elems 8l+4..8l+7
    float sum = a.x * a.x + a.y * a.y + a.z * a.z + a.w * a.w +
                b.x * b.x + b.y * b.y + b.z * b.z + b.w * b.w;
    bf16x8 o;
    o[0] = (__bf16)a.x; o[1] = (__bf16)a.y; o[2] = (__bf16)a.z; o[3] = (__bf16)a.w;
    o[4] = (__bf16)b.x; o[5] = (__bf16)b.y; o[6] = (__bf16)b.z; o[7] = (__bf16)b.w;
    L[r * 64 + ((lane + r) & 63)] = o;  // rotate by r: phase-2 conflict-free
#pragma unroll
    for (int m = 32; m >= 1; m >>= 1) sum += __shfl_xor(sum, m, 64);
    if (lane == 0) nrm[r] = sum;
  }
  __syncthreads();
  // phase 2: frag chunk c = sg*64 + h*32 + r31  <-  L[r31*64 + (sg*2+h+r31)&63]
#pragma unroll
  for (int it = 0; it < 8; ++it) {
    const int c = it * 256 + t;
    const int sg = c >> 6, h = (c >> 5) & 1, r31 = c & 31;
    dstF[c] = L[r31 * 64 + ((sg * 2 + h + r31) & 63)];
  }
}

// B-STATIONARY GEMM. Block = 512 thr (8 waves), handles one 64-row SV chunk
// (cm) x one 1024-row X quarter (nq). SV chunk staged into LDS ONCE (64 KB,
// frag-chunk order = straight contiguous copy); after the single barrier the
// kernel is barrier-free: stream A-frags from global (coalesced 16B/lane,
// R9-verified frag order), B-frags from LDS (contiguous, conflict-free).
// Grid 128x4 = 512 blocks = exactly 2/CU (LDS 128 KB/CU, 16 waves/CU).
// Chip traffic: B 32 MB once + A ~60 MB (16 same-quarter blocks per XCD share
// the stream via L2) vs ~512 MB for the tile-staging designs of R1..R10.
// Waves stack in n: per pass 8x64 = 512 rows; 2 passes cover the quarter.
__global__ __launch_bounds__(512, 4) void rbf_gemm_kernel(
    const bf16x8* __restrict__ Xf, const bf16x8* __restrict__ SVf,
    const float* __restrict__ x2, const float* __restrict__ sv2,
    const float* __restrict__ DC, const float* __restrict__ gamma_p,
    float* __restrict__ out) {
  __shared__ bf16x8 Bs[4096];  // 64 KB: [rg2(2)][sg(32)][lane(64)]

  const int t = threadIdx.x;
  const int lane = t & 63;
  const int wave = t >> 6;  // 0..7
  const int cm = blockIdx.x;  // m-chunk: SV rows [cm*64, cm*64+64)
  const int nq = blockIdx.y;  // n-quarter: X rows [nq*1024, ...)
  const int m0 = cm * 64;
  const int l31 = lane & 31;
  const int lhi = lane >> 5;

  // ---- stage B once: contiguous 64 KB copy (frag region of rg 2cm, 2cm+1)
  const bf16x8* bsrc = SVf + (size_t)cm * 4096;
#pragma unroll
  for (int it = 0; it < 8; ++it) {
    const int c = it * 512 + t;
    load_lds16(bsrc + c, &Bs[c]);
  }
  __syncthreads();  // the ONLY barrier in this kernel

  const float g = gamma_p[0];
  const float c2 = g * 1.4426950408889634f;  // gamma * log2(e)
  float sv2v[2], dcv[2];
  sv2v[0] = sv2[m0 + l31];
  dcv[0] = DC[m0 + l31];
  sv2v[1] = sv2[m0 + 32 + l31];
  dcv[1] = DC[m0 + 32 + l31];

  for (int pass = 0; pass < 2; ++pass) {
    const int nb = nq * 1024 + pass * 512 + wave * 64;  // wave's 64 n-rows
    const bf16x8* ap0 = Xf + (size_t)(nb >> 5) * 2048 + lane;
    const bf16x8* ap1 = ap0 + 2048;

    f32x16 acc[2][2];
#pragma unroll
    for (int i = 0; i < 2; ++i)
#pragma unroll
      for (int j = 0; j < 2; ++j)
#pragma unroll
        for (int r = 0; r < 16; ++r) acc[i][j][r] = 0.0f;

    // K loop: 32 k-slices of 16, no barriers -> compiler pipelines with
    // fine-grained vmcnt/lgkmcnt (launch_bounds caps regs for 4 waves/SIMD).
#pragma unroll
    for (int sg = 0; sg < 32; ++sg) {
      bf16x8 a0 = ap0[(size_t)sg * 64];
      bf16x8 a1 = ap1[(size_t)sg * 64];
      bf16x8 b0 = Bs[sg * 64 + lane];
      bf16x8 b1 = Bs[2048 + sg * 64 + lane];
      acc[0][0] = __builtin_amdgcn_mfma_f32_32x32x16_bf16(a0, b0, acc[0][0], 0, 0, 0);
      acc[0][1] = __builtin_amdgcn_mfma_f32_32x32x16_bf16(a0, b1, acc[0][1], 0, 0, 0);
      acc[1][0] = __builtin_amdgcn_mfma_f32_32x32x16_bf16(a1, b0, acc[1][0], 0, 0, 0);
      acc[1][1] = __builtin_amdgcn_mfma_f32_32x32x16_bf16(a1, b1, acc[1][1], 0, 0, 0);
    }

    // ---- per-pass epilogue (R10-verified math/layout) ----
#pragma unroll
    for (int i = 0; i < 2; ++i) {
      const int rowb = nb + i * 32 + 4 * lhi;  // C row = rowb + 8*g4 + r2
      float val[16];
#pragma unroll
      for (int g4 = 0; g4 < 4; ++g4) {
        f32x4 xv = *(const f32x4*)(x2 + rowb + 8 * g4);
#pragma unroll
        for (int r2 = 0; r2 < 4; ++r2) {
          const int reg = g4 * 4 + r2;
          float v = 0.0f;
#pragma unroll
          for (int j = 0; j < 2; ++j) {
            float d2 = xv[r2] + sv2v[j] - 2.0f * acc[i][j][reg];
            d2 = fmaxf(d2, 0.0f);
            v += exp2f(-c2 * d2) * dcv[j];
          }
          val[reg] = v;
        }
      }
#pragma unroll
      for (int reg = 0; reg < 16; ++reg) {
        float v = val[reg];
        v = dpp_radd<0x121>(v);  // row_ror:1
        v = dpp_radd<0x122>(v);  // row_ror:2
        v = dpp_radd<0x124>(v);  // row_ror:4
        v = dpp_radd<0x128>(v);  // row_ror:8
        val[reg] = swz_add_xor16(v);
      }
      if (l31 == 0) {
#pragma unroll
        for (int g4 = 0; g4 < 4; ++g4)
#pragma unroll
          for (int r2 = 0; r2 < 4; ++r2)
            atomicAdd(&out[rowb + 8 * g4 + r2], val[g4 * 4 + r2]);
      }
    }
  }
}

extern "C" void kernel_launch(void* const* d_in, const int* in_sizes, int n_in,
                              void* d_out, int out_size, void* d_ws, size_t ws_size,
                              hipStream_t stream) {
  const float* X = (const float*)d_in[0];
  const float* SV = (const float*)d_in[1];
  const float* DC = (const float*)d_in[2];
  const float* IC = (const float*)d_in[3];
  const float* gamma = (const float*)d_in[4];
  float* out = (float*)d_out;

  char* ws = (char*)d_ws;
  bf16x8* Xf = (bf16x8*)ws;                                   // 4 MB (frag order)
  bf16x8* SVf = (bf16x8*)(ws + (size_t)NN * DD * 2);          // 8 MB (frag order)
  float* x2 = (float*)(ws + (size_t)(NN + MM) * DD * 2);      // 16 KB
  float* sv2 = x2 + NN;                                       // 32 KB

  convert_norm_kernel<<<(NN + MM) / 32, 256, 0, stream>>>(X, SV, Xf, SVf, x2, sv2, out, IC);
  dim3 grid(MM / 64, NN / 1024);
  rbf_gemm_kernel<<<grid, 512, 0, stream>>>(Xf, SVf, x2, sv2, DC, gamma, out);
}

// Round 12
// 129.068 us; speedup vs baseline: 2.2101x; 2.2101x over previous
//
#include <hip/hip_runtime.h>
#include <stdint.h>

#define NN 4096
#define MM 8192
#define DD 512
#define KT 8  // 512 / BK, BK = 64

typedef __bf16 bf16x8 __attribute__((ext_vector_type(8)));
typedef __bf16 bf16x4 __attribute__((ext_vector_type(4)));
typedef float f32x4 __attribute__((ext_vector_type(4)));
typedef float f32x16 __attribute__((ext_vector_type(16)));

__device__ __forceinline__ void load_lds16(const void* g, void* l) {
  // async global -> LDS, 16B/lane; LDS dest must be wave-uniform base + lane*16.
  __builtin_amdgcn_global_load_lds(
      (const __attribute__((address_space(1))) unsigned int*)g,
      (__attribute__((address_space(3))) unsigned int*)l, 16, 0, 0);
}

// VALU-pipe partial reduction (R7/R8-verified correct): x += rot16(x, k).
template <int CTRL>
__device__ __forceinline__ float dpp_radd(float x) {
  int xi = __float_as_int(x);
  int mv = __builtin_amdgcn_update_dpp(xi, xi, CTRL, 0xF, 0xF, false);
  return x + __int_as_float(mv);
}
__device__ __forceinline__ float swz_add_xor16(float x) {
  int sv = __builtin_amdgcn_ds_swizzle(__float_as_int(x), 0x401F);
  return x + __int_as_float(sv);
}

// 4 rows per 256-thread block, one wave per row. Fully-coalesced f32x4 loads,
// bf16x4 stores, exact fp32 row-norm, and out[]=IC init folded in.
__global__ __launch_bounds__(256) void convert_norm_kernel(
    const float* __restrict__ X, const float* __restrict__ SV,
    __bf16* __restrict__ Xb, __bf16* __restrict__ SVb,
    float* __restrict__ x2, float* __restrict__ sv2,
    float* __restrict__ out, const float* __restrict__ IC) {
  int wid = blockIdx.x * 4 + (threadIdx.x >> 6);
  int lane = threadIdx.x & 63;
  const float* src;
  __bf16* dst;
  float* nrm;
  if (wid < NN) {
    src = X + (size_t)wid * DD;
    dst = Xb + (size_t)wid * DD;
    nrm = x2 + wid;
    if (lane == 0) out[wid] = IC[0];
  } else {
    int r = wid - NN;
    src = SV + (size_t)r * DD;
    dst = SVb + (size_t)r * DD;
    nrm = sv2 + r;
  }
  const f32x4* s = (const f32x4*)src;
  f32x4 a = s[lane];       // elements 4l..4l+3
  f32x4 b = s[lane + 64];  // elements 256+4l..
  float sum = a.x * a.x + a.y * a.y + a.z * a.z + a.w * a.w +
              b.x * b.x + b.y * b.y + b.z * b.z + b.w * b.w;
  bf16x4 ca = {(__bf16)a.x, (__bf16)a.y, (__bf16)a.z, (__bf16)a.w};
  bf16x4 cb = {(__bf16)b.x, (__bf16)b.y, (__bf16)b.z, (__bf16)b.w};
  *(bf16x4*)(dst + 4 * lane) = ca;
  *(bf16x4*)(dst + 256 + 4 * lane) = cb;
#pragma unroll
  for (int m = 32; m >= 1; m >>= 1) sum += __shfl_xor(sum, m, 64);
  if (lane == 0) *nrm = sum;
}

// R4 structure verbatim (champion: 64.4 us, 534 TF — at the m102
// size-adjusted plateau of the m97 family): 128x128 tile, BK=64, 4 waves
// (2x2), each wave 64x64 via 2x2 of mfma_f32_32x32x16_bf16, single 32 KB
// LDS buffer -> 4 blocks/CU; cross-block wave overlap hides staging.
// ONLY change vs R4: the epilogue's 5-level __shfl_xor LDS tree (160
// LDS-network ops/wave, ~10 us/CU of phase-locked LDS-pipe work) is
// replaced by 4 DPP row_ror adds (VALU pipe) + one ds_swizzle xor16
// (32 LDS ops/wave). DPP path correctness verified in R7/R8.
__global__ __launch_bounds__(256, 4) void rbf_gemm_kernel(
    const bf16x8* __restrict__ Xb, const bf16x8* __restrict__ SVb,
    const float* __restrict__ x2, const float* __restrict__ sv2,
    const float* __restrict__ DC, const float* __restrict__ gamma_p,
    float* __restrict__ out) {
  __shared__ bf16x8 As[1024];  // 16 KB
  __shared__ bf16x8 Bs[1024];  // 16 KB

  const int t = threadIdx.x;
  const int lane = t & 63;
  const int wave = t >> 6;
  const int n0 = blockIdx.x * 128;
  const int m0 = blockIdx.y * 128;

  const int wave_m = wave & 1;   // m-dir of C
  const int wave_n = wave >> 1;  // n-dir of C
  const int l31 = lane & 31;
  const int lhi = lane >> 5;

  // staging decomposition: chunk c_it = it*256 + t
  const int srow = t >> 3;            // row contribution for it=0 (rows 0..31)
  const int sslot = t & 7;

  f32x16 acc[2][2];
#pragma unroll
  for (int i = 0; i < 2; ++i)
#pragma unroll
    for (int j = 0; j < 2; ++j)
#pragma unroll
      for (int r = 0; r < 16; ++r) acc[i][j][r] = 0.0f;

  for (int kt = 0; kt < KT; ++kt) {
    // ---- cooperative staging: 4 instrs A + 4 instrs B per thread ----
#pragma unroll
    for (int it = 0; it < 4; ++it) {
      const int c = it * 256 + t;
      const int row = it * 32 + srow;
      const int kg = sslot ^ (row & 7);
      load_lds16(Xb + (size_t)(n0 + row) * 64 + kt * 8 + kg, &As[c]);
      load_lds16(SVb + (size_t)(m0 + row) * 64 + kt * 8 + kg, &Bs[c]);
    }
    __syncthreads();
    // ---- compute ----
#pragma unroll
    for (int ks = 0; ks < 4; ++ks) {
      const int kc = ks * 2 + lhi;        // k-chunk 0..7
      const int sw = kc ^ (l31 & 7);
      const int ra = (wave_n * 64 + l31) * 8;
      const int rb = (wave_m * 64 + l31) * 8;
      bf16x8 af0 = As[ra + sw];
      bf16x8 af1 = As[ra + 256 + sw];  // +32 rows
      bf16x8 bf0 = Bs[rb + sw];
      bf16x8 bf1 = Bs[rb + 256 + sw];
      acc[0][0] = __builtin_amdgcn_mfma_f32_32x32x16_bf16(af0, bf0, acc[0][0], 0, 0, 0);
      acc[0][1] = __builtin_amdgcn_mfma_f32_32x32x16_bf16(af0, bf1, acc[0][1], 0, 0, 0);
      acc[1][0] = __builtin_amdgcn_mfma_f32_32x32x16_bf16(af1, bf0, acc[1][0], 0, 0, 0);
      acc[1][1] = __builtin_amdgcn_mfma_f32_32x32x16_bf16(af1, bf1, acc[1][1], 0, 0, 0);
    }
    __syncthreads();
  }

  // ---- epilogue (no barriers) ----
  const float g = gamma_p[0];
  const float c2 = g * 1.4426950408889634f;  // gamma * log2(e)

  float sv2v[2], dcv[2];
  const int colb = m0 + wave_m * 64 + l31;
  sv2v[0] = sv2[colb];
  dcv[0] = DC[colb];
  sv2v[1] = sv2[colb + 32];
  dcv[1] = DC[colb + 32];

#pragma unroll
  for (int i = 0; i < 2; ++i) {
    // C row = rowb + 8*g4 + r2, where reg = g4*4 + r2
    const int rowb = n0 + wave_n * 64 + i * 32 + 4 * lhi;
    float val[16];
#pragma unroll
    for (int g4 = 0; g4 < 4; ++g4) {
      f32x4 xv = *(const f32x4*)(x2 + rowb + 8 * g4);
#pragma unroll
      for (int r2 = 0; r2 < 4; ++r2) {
        const int reg = g4 * 4 + r2;
        float v = 0.0f;
#pragma unroll
        for (int j = 0; j < 2; ++j) {
          float d2 = xv[r2] + sv2v[j] - 2.0f * acc[i][j][reg];
          d2 = fmaxf(d2, 0.0f);
          v += exp2f(-c2 * d2) * dcv[j];
        }
        val[reg] = v;
      }
    }
    // reduce over 32 column-lanes: 4 DPP row-rotations (VALU pipe) + one
    // ds_swizzle xor16 (R7/R8-verified) — replaces 160 LDS-ops/wave with 32.
#pragma unroll
    for (int reg = 0; reg < 16; ++reg) {
      float v = val[reg];
      v = dpp_radd<0x121>(v);  // row_ror:1
      v = dpp_radd<0x122>(v);  // row_ror:2
      v = dpp_radd<0x124>(v);  // row_ror:4
      v = dpp_radd<0x128>(v);  // row_ror:8
      val[reg] = swz_add_xor16(v);
    }
    if (l31 == 0) {
#pragma unroll
      for (int g4 = 0; g4 < 4; ++g4)
#pragma unroll
        for (int r2 = 0; r2 < 4; ++r2)
          atomicAdd(&out[rowb + 8 * g4 + r2], val[g4 * 4 + r2]);
    }
  }
}

extern "C" void kernel_launch(void* const* d_in, const int* in_sizes, int n_in,
                              void* d_out, int out_size, void* d_ws, size_t ws_size,
                              hipStream_t stream) {
  const float* X = (const float*)d_in[0];
  const float* SV = (const float*)d_in[1];
  const float* DC = (const float*)d_in[2];
  const float* IC = (const float*)d_in[3];
  const float* gamma = (const float*)d_in[4];
  float* out = (float*)d_out;

  char* ws = (char*)d_ws;
  __bf16* Xb = (__bf16*)ws;                                   // 4 MB
  __bf16* SVb = (__bf16*)(ws + (size_t)NN * DD * 2);          // 8 MB
  float* x2 = (float*)(ws + (size_t)(NN + MM) * DD * 2);      // 16 KB
  float* sv2 = x2 + NN;                                       // 32 KB

  convert_norm_kernel<<<(NN + MM) / 4, 256, 0, stream>>>(X, SV, Xb, SVb, x2, sv2, out, IC);
  dim3 grid(NN / 128, MM / 128);
  rbf_gemm_kernel<<<grid, 256, 0, stream>>>((const bf16x8*)Xb, (const bf16x8*)SVb,
                                            x2, sv2, DC, gamma, out);
}